// Round 1
// baseline (2495.617 us; speedup 1.0000x reference)
//
#include <hip/hip_runtime.h>

// DeepfakeGNN: 2-layer GCN (self-loops, symmetric norm) + mean-pool + linear.
// Round 0: correctness-first fp32. Atomic-scatter aggregation, LDS-tiled SGEMM.

#define TPB 256

__global__ __launch_bounds__(TPB) void k_zero_i32(int* p, int n) {
  int i = blockIdx.x * TPB + threadIdx.x;
  if (i < n) p[i] = 0;
}

__global__ __launch_bounds__(TPB) void k_zero_f32(float* p, int n) {
  int i = blockIdx.x * TPB + threadIdx.x;
  if (i < n) p[i] = 0.f;
}

__global__ __launch_bounds__(TPB) void k_count(const int* __restrict__ dst,
                                               int* __restrict__ cnt, int E) {
  int e = blockIdx.x * TPB + threadIdx.x;
  if (e < E) atomicAdd(&cnt[dst[e]], 1);
}

__global__ __launch_bounds__(TPB) void k_dinv(const int* __restrict__ cnt,
                                              float* __restrict__ dinv, int N) {
  int i = blockIdx.x * TPB + threadIdx.x;
  if (i < N) dinv[i] = rsqrtf((float)(cnt[i] + 1));  // +1 self loop; always > 0
}

// C[M,N] = A[M,K] @ B[K,N].  Requires N%64==0, K%16==0 (true: N=256, K in {512,256}).
// BM=BN=64, BK=16, 256 threads, 4x4 per thread. As stored [k][row] for
// conflict-free ds_read_b128 in the inner loop.
__global__ __launch_bounds__(TPB) void k_gemm(const float* __restrict__ A,
                                              const float* __restrict__ B,
                                              float* __restrict__ C,
                                              int M, int N, int K) {
  __shared__ float As[16][64];
  __shared__ float Bs[16][64];
  const int tid = threadIdx.x;
  const int tx = tid & 15;        // 0..15 -> col group
  const int ty = tid >> 4;        // 0..15 -> row group
  const int bx = blockIdx.x;      // along N
  const int by = blockIdx.y;      // along M
  // A-load mapping: row = tid&63, k offset = (tid>>6)*4  (float4 loads)
  const int lr  = tid & 63;
  const int lk  = (tid >> 6) << 2;
  // B-load mapping: k row = tid>>4, col offset = (tid&15)*4
  const int bkr = tid >> 4;
  const int bc  = (tid & 15) << 2;
  const int arow = by * 64 + lr;
  const float* Aptr = A + (size_t)arow * K + lk;
  const float* Bptr = B + (size_t)bkr * N + bx * 64 + bc;

  float acc[4][4] = {{0.f}};

  for (int k0 = 0; k0 < K; k0 += 16) {
    float4 av = make_float4(0.f, 0.f, 0.f, 0.f);
    if (arow < M) av = *(const float4*)(Aptr + k0);
    float4 bv = *(const float4*)(Bptr + (size_t)k0 * N);
    __syncthreads();
    As[lk + 0][lr] = av.x;
    As[lk + 1][lr] = av.y;
    As[lk + 2][lr] = av.z;
    As[lk + 3][lr] = av.w;
    *(float4*)&Bs[bkr][bc] = bv;
    __syncthreads();
#pragma unroll
    for (int kk = 0; kk < 16; ++kk) {
      const float4 a = *(const float4*)&As[kk][ty << 2];
      const float4 b = *(const float4*)&Bs[kk][tx << 2];
      acc[0][0] = fmaf(a.x, b.x, acc[0][0]);
      acc[0][1] = fmaf(a.x, b.y, acc[0][1]);
      acc[0][2] = fmaf(a.x, b.z, acc[0][2]);
      acc[0][3] = fmaf(a.x, b.w, acc[0][3]);
      acc[1][0] = fmaf(a.y, b.x, acc[1][0]);
      acc[1][1] = fmaf(a.y, b.y, acc[1][1]);
      acc[1][2] = fmaf(a.y, b.z, acc[1][2]);
      acc[1][3] = fmaf(a.y, b.w, acc[1][3]);
      acc[2][0] = fmaf(a.z, b.x, acc[2][0]);
      acc[2][1] = fmaf(a.z, b.y, acc[2][1]);
      acc[2][2] = fmaf(a.z, b.z, acc[2][2]);
      acc[2][3] = fmaf(a.z, b.w, acc[2][3]);
      acc[3][0] = fmaf(a.w, b.x, acc[3][0]);
      acc[3][1] = fmaf(a.w, b.y, acc[3][1]);
      acc[3][2] = fmaf(a.w, b.z, acc[3][2]);
      acc[3][3] = fmaf(a.w, b.w, acc[3][3]);
    }
  }

  const int row0 = by * 64 + (ty << 2);
  const int col0 = bx * 64 + (tx << 2);
#pragma unroll
  for (int i = 0; i < 4; ++i) {
    if (row0 + i < M) {
      float4 v = make_float4(acc[i][0], acc[i][1], acc[i][2], acc[i][3]);
      *(float4*)&C[(size_t)(row0 + i) * N + col0] = v;
    }
  }
}

// agg[i,:] = dinv[i]^2 * xw[i,:]   (self-loop term; unique writer per row)
// one wave per node, lane -> 4 floats. D_H = 256 hard-wired (64 lanes * 4).
__global__ __launch_bounds__(TPB) void k_self(const float* __restrict__ xw,
                                              const float* __restrict__ dinv,
                                              float* __restrict__ agg, int N) {
  int t = blockIdx.x * TPB + threadIdx.x;
  int i = t >> 6;
  if (i >= N) return;
  int c = (t & 63) << 2;
  float d = dinv[i];
  float s = d * d;
  const float4 v = *(const float4*)&xw[(size_t)i * 256 + c];
  float4 o = make_float4(v.x * s, v.y * s, v.z * s, v.w * s);
  *(float4*)&agg[(size_t)i * 256 + c] = o;
}

// agg[dst,:] += dinv[src]*dinv[dst] * xw[src,:]   (one wave per edge)
__global__ __launch_bounds__(TPB) void k_edge(const int* __restrict__ src,
                                              const int* __restrict__ dst,
                                              const float* __restrict__ dinv,
                                              const float* __restrict__ xw,
                                              float* __restrict__ agg, int E) {
  int t = blockIdx.x * TPB + threadIdx.x;
  int e = t >> 6;
  if (e >= E) return;
  int c = (t & 63) << 2;
  int s = src[e];
  int d = dst[e];
  float coef = dinv[s] * dinv[d];
  const float4 v = *(const float4*)&xw[(size_t)s * 256 + c];
  float* o = &agg[(size_t)d * 256 + c];
  atomicAdd(o + 0, v.x * coef);
  atomicAdd(o + 1, v.y * coef);
  atomicAdd(o + 2, v.z * coef);
  atomicAdd(o + 3, v.w * coef);
}

// h = relu(h + b)   in place
__global__ __launch_bounds__(TPB) void k_bias_relu(float* __restrict__ h,
                                                   const float* __restrict__ b,
                                                   int N) {
  int t = blockIdx.x * TPB + threadIdx.x;
  int i = t >> 6;
  if (i >= N) return;
  int c = (t & 63) << 2;
  float4 v = *(float4*)&h[(size_t)i * 256 + c];
  const float4 bb = *(const float4*)&b[c];
  v.x = fmaxf(v.x + bb.x, 0.f);
  v.y = fmaxf(v.y + bb.y, 0.f);
  v.z = fmaxf(v.z + bb.z, 0.f);
  v.w = fmaxf(v.w + bb.w, 0.f);
  *(float4*)&h[(size_t)i * 256 + c] = v;
}

// per-node dot(h2[i,:], w_fc) -> atomic segment sums + counts (wave per node)
__global__ __launch_bounds__(TPB) void k_pool(const float* __restrict__ h,
                                              const float* __restrict__ wfc,
                                              const int* __restrict__ batch,
                                              float* __restrict__ sums,
                                              int* __restrict__ gcnt, int N) {
  int t = blockIdx.x * TPB + threadIdx.x;
  int i = t >> 6;
  if (i >= N) return;
  int lane = t & 63;
  int c = lane << 2;
  const float4 v = *(const float4*)&h[(size_t)i * 256 + c];
  const float4 f = *(const float4*)&wfc[c];
  float s = v.x * f.x + v.y * f.y + v.z * f.z + v.w * f.w;
#pragma unroll
  for (int off = 32; off > 0; off >>= 1) s += __shfl_down(s, off);
  if (lane == 0) {
    int g = batch[i];
    atomicAdd(&sums[g], s);
    atomicAdd(&gcnt[g], 1);
  }
}

__global__ __launch_bounds__(TPB) void k_final(const float* __restrict__ sums,
                                               const int* __restrict__ gcnt,
                                               const float* __restrict__ bfc,
                                               float* __restrict__ out, int G) {
  int g = blockIdx.x * TPB + threadIdx.x;
  if (g >= G) return;
  float c = (float)gcnt[g];
  out[g] = sums[g] / fmaxf(c, 1.f) + bfc[0];
}

extern "C" void kernel_launch(void* const* d_in, const int* in_sizes, int n_in,
                              void* d_out, int out_size, void* d_ws, size_t ws_size,
                              hipStream_t stream) {
  const float* x    = (const float*)d_in[0];
  const int*   eidx = (const int*)d_in[1];
  const int*   batch= (const int*)d_in[2];
  const float* W1   = (const float*)d_in[3];
  const float* b1   = (const float*)d_in[4];
  const float* W2   = (const float*)d_in[5];
  const float* b2   = (const float*)d_in[6];
  const float* wfc  = (const float*)d_in[7];
  const float* bfc  = (const float*)d_in[8];
  float* out = (float*)d_out;

  const int N  = in_sizes[2];        // 20000
  const int E  = in_sizes[1] / 2;    // 320000
  const int K1 = in_sizes[0] / N;    // 512
  const int DH = in_sizes[4];        // 256 (kernels hard-wire 256 row stride)
  const int G  = out_size;           // 128

  const int* srcp = eidx;
  const int* dstp = eidx + E;

  // workspace layout
  char* ws = (char*)d_ws;
  int*   cnt  = (int*)ws;                                       // N ints
  float* dinv = (float*)(ws + (size_t)N * 4);                   // N floats
  float* sums = (float*)(ws + (size_t)2 * N * 4);               // G floats
  int*   gcnt = (int*)(ws + (size_t)2 * N * 4 + (size_t)G * 4); // G ints
  float* bufA = (float*)(ws + (size_t)2 * N * 4 + (size_t)2 * G * 4);
  float* bufB = bufA + (size_t)N * DH;

  const int nb_N  = (N + TPB - 1) / TPB;
  const int nb_E  = (E + TPB - 1) / TPB;
  const int nt    = N * 64;                 // wave per node
  const int nb_nt = (nt + TPB - 1) / TPB;
  const int et    = E * 64;                 // wave per edge
  const int nb_et = (et + TPB - 1) / TPB;

  // degrees -> dinv
  k_zero_i32<<<nb_N, TPB, 0, stream>>>(cnt, N);
  k_count<<<nb_E, TPB, 0, stream>>>(dstp, cnt, E);
  k_dinv<<<nb_N, TPB, 0, stream>>>(cnt, dinv, N);

  // layer 1: xw1 = x @ W1 -> bufA ; aggregate -> bufB ; relu(+b1) in place
  dim3 g1(DH / 64, (N + 63) / 64);
  k_gemm<<<g1, TPB, 0, stream>>>(x, W1, bufA, N, DH, K1);
  k_self<<<nb_nt, TPB, 0, stream>>>(bufA, dinv, bufB, N);
  k_edge<<<nb_et, TPB, 0, stream>>>(srcp, dstp, dinv, bufA, bufB, E);
  k_bias_relu<<<nb_nt, TPB, 0, stream>>>(bufB, b1, N);

  // layer 2: xw2 = h1 @ W2 -> bufA ; aggregate -> bufB ; relu(+b2) in place
  k_gemm<<<g1, TPB, 0, stream>>>(bufB, W2, bufA, N, DH, DH);
  k_self<<<nb_nt, TPB, 0, stream>>>(bufA, dinv, bufB, N);
  k_edge<<<nb_et, TPB, 0, stream>>>(srcp, dstp, dinv, bufA, bufB, E);
  k_bias_relu<<<nb_nt, TPB, 0, stream>>>(bufB, b2, N);

  // pooling + fc
  k_zero_f32<<<(G + TPB - 1) / TPB, TPB, 0, stream>>>(sums, G);
  k_zero_i32<<<(G + TPB - 1) / TPB, TPB, 0, stream>>>(gcnt, G);
  k_pool<<<nb_nt, TPB, 0, stream>>>(bufB, wfc, batch, sums, gcnt, N);
  k_final<<<(G + TPB - 1) / TPB, TPB, 0, stream>>>(sums, gcnt, bfc, out, G);
}

// Round 2
// 453.899 us; speedup vs baseline: 5.4982x; 5.4982x over previous
//
#include <hip/hip_runtime.h>

// DeepfakeGNN: 2-layer GCN (self-loops, symmetric norm) + mean-pool + linear.
// Round 1 -> 2: replace atomic edge-scatter (2x1080us, 87M fp32 atomics/layer)
// with CSR-by-dst build + register-accumulating gather (wave per node).
// Fuse bias+relu into gather; fuse pooling dot into layer-2 gather (h2 never hits HBM).

#define TPB 256

__global__ __launch_bounds__(TPB) void k_zero_i32(int* p, int n) {
  int i = blockIdx.x * TPB + threadIdx.x;
  if (i < n) p[i] = 0;
}

__global__ __launch_bounds__(TPB) void k_zero_f32(float* p, int n) {
  int i = blockIdx.x * TPB + threadIdx.x;
  if (i < n) p[i] = 0.f;
}

__global__ __launch_bounds__(TPB) void k_count(const int* __restrict__ dst,
                                               int* __restrict__ cnt, int E) {
  int e = blockIdx.x * TPB + threadIdx.x;
  if (e < E) atomicAdd(&cnt[dst[e]], 1);
}

__global__ __launch_bounds__(TPB) void k_dinv(const int* __restrict__ cnt,
                                              float* __restrict__ dinv, int N) {
  int i = blockIdx.x * TPB + threadIdx.x;
  if (i < N) dinv[i] = rsqrtf((float)(cnt[i] + 1));  // +1 self loop; always > 0
}

// exclusive prefix sum of cnt[0..N) -> rowptr[0..N], single workgroup (N=20000).
__global__ __launch_bounds__(1024) void k_scan(const int* __restrict__ cnt,
                                               int* __restrict__ rowptr, int N) {
  __shared__ int buf[1024];
  __shared__ int carry;
  if (threadIdx.x == 0) carry = 0;
  __syncthreads();
  for (int base = 0; base < N; base += 1024) {
    int i = base + threadIdx.x;
    int v = (i < N) ? cnt[i] : 0;
    buf[threadIdx.x] = v;
    __syncthreads();
#pragma unroll
    for (int off = 1; off < 1024; off <<= 1) {
      int t = (threadIdx.x >= off) ? buf[threadIdx.x - off] : 0;
      __syncthreads();
      buf[threadIdx.x] += t;
      __syncthreads();
    }
    int incl = buf[threadIdx.x];
    if (i < N) rowptr[i] = carry + incl - v;
    __syncthreads();                      // everyone has read carry
    if (threadIdx.x == 1023) carry += incl;
    __syncthreads();
  }
  if (threadIdx.x == 0) rowptr[N] = carry;
}

// scatter edges into CSR slots: col[pos]=src, val[pos]=dinv[src]*dinv[dst]
__global__ __launch_bounds__(TPB) void k_scatter(const int* __restrict__ src,
                                                 const int* __restrict__ dst,
                                                 const float* __restrict__ dinv,
                                                 const int* __restrict__ rowptr,
                                                 int* __restrict__ cursor,
                                                 int* __restrict__ col,
                                                 float* __restrict__ val, int E) {
  int e = blockIdx.x * TPB + threadIdx.x;
  if (e >= E) return;
  int s = src[e], d = dst[e];
  int pos = rowptr[d] + atomicAdd(&cursor[d], 1);
  col[pos] = s;
  val[pos] = dinv[s] * dinv[d];
}

// C[M,N] = A[M,K] @ B[K,N].  N%64==0, K%16==0 (N=256, K in {512,256}).
__global__ __launch_bounds__(TPB) void k_gemm(const float* __restrict__ A,
                                              const float* __restrict__ B,
                                              float* __restrict__ C,
                                              int M, int N, int K) {
  __shared__ float As[16][64];
  __shared__ float Bs[16][64];
  const int tid = threadIdx.x;
  const int tx = tid & 15;
  const int ty = tid >> 4;
  const int bx = blockIdx.x;
  const int by = blockIdx.y;
  const int lr  = tid & 63;
  const int lk  = (tid >> 6) << 2;
  const int bkr = tid >> 4;
  const int bc  = (tid & 15) << 2;
  const int arow = by * 64 + lr;
  const float* Aptr = A + (size_t)arow * K + lk;
  const float* Bptr = B + (size_t)bkr * N + bx * 64 + bc;

  float acc[4][4] = {{0.f}};

  for (int k0 = 0; k0 < K; k0 += 16) {
    float4 av = make_float4(0.f, 0.f, 0.f, 0.f);
    if (arow < M) av = *(const float4*)(Aptr + k0);
    float4 bv = *(const float4*)(Bptr + (size_t)k0 * N);
    __syncthreads();
    As[lk + 0][lr] = av.x;
    As[lk + 1][lr] = av.y;
    As[lk + 2][lr] = av.z;
    As[lk + 3][lr] = av.w;
    *(float4*)&Bs[bkr][bc] = bv;
    __syncthreads();
#pragma unroll
    for (int kk = 0; kk < 16; ++kk) {
      const float4 a = *(const float4*)&As[kk][ty << 2];
      const float4 b = *(const float4*)&Bs[kk][tx << 2];
      acc[0][0] = fmaf(a.x, b.x, acc[0][0]);
      acc[0][1] = fmaf(a.x, b.y, acc[0][1]);
      acc[0][2] = fmaf(a.x, b.z, acc[0][2]);
      acc[0][3] = fmaf(a.x, b.w, acc[0][3]);
      acc[1][0] = fmaf(a.y, b.x, acc[1][0]);
      acc[1][1] = fmaf(a.y, b.y, acc[1][1]);
      acc[1][2] = fmaf(a.y, b.z, acc[1][2]);
      acc[1][3] = fmaf(a.y, b.w, acc[1][3]);
      acc[2][0] = fmaf(a.z, b.x, acc[2][0]);
      acc[2][1] = fmaf(a.z, b.y, acc[2][1]);
      acc[2][2] = fmaf(a.z, b.z, acc[2][2]);
      acc[2][3] = fmaf(a.z, b.w, acc[2][3]);
      acc[3][0] = fmaf(a.w, b.x, acc[3][0]);
      acc[3][1] = fmaf(a.w, b.y, acc[3][1]);
      acc[3][2] = fmaf(a.w, b.z, acc[3][2]);
      acc[3][3] = fmaf(a.w, b.w, acc[3][3]);
    }
  }

  const int row0 = by * 64 + (ty << 2);
  const int col0 = bx * 64 + (tx << 2);
#pragma unroll
  for (int i = 0; i < 4; ++i) {
    if (row0 + i < M) {
      float4 v = make_float4(acc[i][0], acc[i][1], acc[i][2], acc[i][3]);
      *(float4*)&C[(size_t)(row0 + i) * N + col0] = v;
    }
  }
}

// Layer gather: out[i,:] = relu( dinv[i]^2*xw[i,:] + sum_k val[k]*xw[col[k],:] + bias )
// one wave per node; lane -> 4 contiguous floats of the 256-wide row.
__global__ __launch_bounds__(TPB) void k_gather(const float* __restrict__ xw,
                                                const float* __restrict__ dinv,
                                                const int* __restrict__ rowptr,
                                                const int* __restrict__ col,
                                                const float* __restrict__ val,
                                                const float* __restrict__ bias,
                                                float* __restrict__ out, int N) {
  int t = blockIdx.x * TPB + threadIdx.x;
  int i = t >> 6;
  if (i >= N) return;
  int c = (t & 63) << 2;
  float di = dinv[i];
  float4 acc = *(const float4*)&xw[(size_t)i * 256 + c];
  float s0 = di * di;
  acc.x *= s0; acc.y *= s0; acc.z *= s0; acc.w *= s0;
  int k = rowptr[i], end = rowptr[i + 1];
  // 2-deep unroll for latency hiding
  for (; k + 1 < end; k += 2) {
    int j0 = col[k], j1 = col[k + 1];
    float c0 = val[k], c1 = val[k + 1];
    const float4 v0 = *(const float4*)&xw[(size_t)j0 * 256 + c];
    const float4 v1 = *(const float4*)&xw[(size_t)j1 * 256 + c];
    acc.x = fmaf(c0, v0.x, acc.x); acc.y = fmaf(c0, v0.y, acc.y);
    acc.z = fmaf(c0, v0.z, acc.z); acc.w = fmaf(c0, v0.w, acc.w);
    acc.x = fmaf(c1, v1.x, acc.x); acc.y = fmaf(c1, v1.y, acc.y);
    acc.z = fmaf(c1, v1.z, acc.z); acc.w = fmaf(c1, v1.w, acc.w);
  }
  if (k < end) {
    int j0 = col[k]; float c0 = val[k];
    const float4 v0 = *(const float4*)&xw[(size_t)j0 * 256 + c];
    acc.x = fmaf(c0, v0.x, acc.x); acc.y = fmaf(c0, v0.y, acc.y);
    acc.z = fmaf(c0, v0.z, acc.z); acc.w = fmaf(c0, v0.w, acc.w);
  }
  const float4 bb = *(const float4*)&bias[c];
  acc.x = fmaxf(acc.x + bb.x, 0.f);
  acc.y = fmaxf(acc.y + bb.y, 0.f);
  acc.z = fmaxf(acc.z + bb.z, 0.f);
  acc.w = fmaxf(acc.w + bb.w, 0.f);
  *(float4*)&out[(size_t)i * 256 + c] = acc;
}

// Layer-2 gather fused with pooling: compute h2 row in registers, then
// s_i = dot(relu(row+b2), wfc); atomicAdd(sums[batch[i]], s_i). h2 never stored.
__global__ __launch_bounds__(TPB) void k_gather_pool(const float* __restrict__ xw,
                                                     const float* __restrict__ dinv,
                                                     const int* __restrict__ rowptr,
                                                     const int* __restrict__ col,
                                                     const float* __restrict__ val,
                                                     const float* __restrict__ bias,
                                                     const float* __restrict__ wfc,
                                                     const int* __restrict__ batch,
                                                     float* __restrict__ sums,
                                                     int* __restrict__ gcnt, int N) {
  int t = blockIdx.x * TPB + threadIdx.x;
  int i = t >> 6;
  if (i >= N) return;
  int lane = t & 63;
  int c = lane << 2;
  float di = dinv[i];
  float4 acc = *(const float4*)&xw[(size_t)i * 256 + c];
  float s0 = di * di;
  acc.x *= s0; acc.y *= s0; acc.z *= s0; acc.w *= s0;
  int k = rowptr[i], end = rowptr[i + 1];
  for (; k + 1 < end; k += 2) {
    int j0 = col[k], j1 = col[k + 1];
    float c0 = val[k], c1 = val[k + 1];
    const float4 v0 = *(const float4*)&xw[(size_t)j0 * 256 + c];
    const float4 v1 = *(const float4*)&xw[(size_t)j1 * 256 + c];
    acc.x = fmaf(c0, v0.x, acc.x); acc.y = fmaf(c0, v0.y, acc.y);
    acc.z = fmaf(c0, v0.z, acc.z); acc.w = fmaf(c0, v0.w, acc.w);
    acc.x = fmaf(c1, v1.x, acc.x); acc.y = fmaf(c1, v1.y, acc.y);
    acc.z = fmaf(c1, v1.z, acc.z); acc.w = fmaf(c1, v1.w, acc.w);
  }
  if (k < end) {
    int j0 = col[k]; float c0 = val[k];
    const float4 v0 = *(const float4*)&xw[(size_t)j0 * 256 + c];
    acc.x = fmaf(c0, v0.x, acc.x); acc.y = fmaf(c0, v0.y, acc.y);
    acc.z = fmaf(c0, v0.z, acc.z); acc.w = fmaf(c0, v0.w, acc.w);
  }
  const float4 bb = *(const float4*)&bias[c];
  acc.x = fmaxf(acc.x + bb.x, 0.f);
  acc.y = fmaxf(acc.y + bb.y, 0.f);
  acc.z = fmaxf(acc.z + bb.z, 0.f);
  acc.w = fmaxf(acc.w + bb.w, 0.f);
  const float4 f = *(const float4*)&wfc[c];
  float s = acc.x * f.x + acc.y * f.y + acc.z * f.z + acc.w * f.w;
#pragma unroll
  for (int off = 32; off > 0; off >>= 1) s += __shfl_down(s, off);
  if (lane == 0) {
    int g = batch[i];
    atomicAdd(&sums[g], s);
    atomicAdd(&gcnt[g], 1);
  }
}

__global__ __launch_bounds__(TPB) void k_final(const float* __restrict__ sums,
                                               const int* __restrict__ gcnt,
                                               const float* __restrict__ bfc,
                                               float* __restrict__ out, int G) {
  int g = blockIdx.x * TPB + threadIdx.x;
  if (g >= G) return;
  float c = (float)gcnt[g];
  out[g] = sums[g] / fmaxf(c, 1.f) + bfc[0];
}

extern "C" void kernel_launch(void* const* d_in, const int* in_sizes, int n_in,
                              void* d_out, int out_size, void* d_ws, size_t ws_size,
                              hipStream_t stream) {
  const float* x    = (const float*)d_in[0];
  const int*   eidx = (const int*)d_in[1];
  const int*   batch= (const int*)d_in[2];
  const float* W1   = (const float*)d_in[3];
  const float* b1   = (const float*)d_in[4];
  const float* W2   = (const float*)d_in[5];
  const float* b2   = (const float*)d_in[6];
  const float* wfc  = (const float*)d_in[7];
  const float* bfc  = (const float*)d_in[8];
  float* out = (float*)d_out;

  const int N  = in_sizes[2];        // 20000
  const int E  = in_sizes[1] / 2;    // 320000
  const int K1 = in_sizes[0] / N;    // 512
  const int DH = in_sizes[4];        // 256 (kernels hard-wire 256 row stride)
  const int G  = out_size;           // 128

  const int* srcp = eidx;
  const int* dstp = eidx + E;

  // workspace layout (all 4-byte types)
  char* ws = (char*)d_ws;
  size_t off = 0;
  int*   cnt    = (int*)(ws + off);   off += (size_t)N * 4;
  float* dinv   = (float*)(ws + off); off += (size_t)N * 4;
  int*   rowptr = (int*)(ws + off);   off += (size_t)(N + 1) * 4;
  int*   cursor = (int*)(ws + off);   off += (size_t)N * 4;
  int*   colA   = (int*)(ws + off);   off += (size_t)E * 4;
  float* valA   = (float*)(ws + off); off += (size_t)E * 4;
  float* sums   = (float*)(ws + off); off += (size_t)G * 4;
  int*   gcnt   = (int*)(ws + off);   off += (size_t)G * 4;
  float* bufA   = (float*)(ws + off); off += (size_t)N * DH * 4;
  float* bufB   = (float*)(ws + off); off += (size_t)N * DH * 4;

  const int nb_N  = (N + TPB - 1) / TPB;
  const int nb_E  = (E + TPB - 1) / TPB;
  const int nt    = N * 64;                 // wave per node
  const int nb_nt = (nt + TPB - 1) / TPB;

  // --- CSR build (by dst) + dinv ---
  k_zero_i32<<<nb_N, TPB, 0, stream>>>(cnt, N);
  k_count<<<nb_E, TPB, 0, stream>>>(dstp, cnt, E);
  k_dinv<<<nb_N, TPB, 0, stream>>>(cnt, dinv, N);
  k_scan<<<1, 1024, 0, stream>>>(cnt, rowptr, N);
  k_zero_i32<<<nb_N, TPB, 0, stream>>>(cursor, N);
  k_scatter<<<nb_E, TPB, 0, stream>>>(srcp, dstp, dinv, rowptr, cursor, colA, valA, E);

  // --- layer 1 ---
  dim3 g1(DH / 64, (N + 63) / 64);
  k_gemm<<<g1, TPB, 0, stream>>>(x, W1, bufA, N, DH, K1);
  k_gather<<<nb_nt, TPB, 0, stream>>>(bufA, dinv, rowptr, colA, valA, b1, bufB, N);

  // --- layer 2 (+ fused pooling) ---
  k_gemm<<<g1, TPB, 0, stream>>>(bufB, W2, bufA, N, DH, DH);
  k_zero_f32<<<(G + TPB - 1) / TPB, TPB, 0, stream>>>(sums, G);
  k_zero_i32<<<(G + TPB - 1) / TPB, TPB, 0, stream>>>(gcnt, G);
  k_gather_pool<<<nb_nt, TPB, 0, stream>>>(bufA, dinv, rowptr, colA, valA, b2,
                                           wfc, batch, sums, gcnt, N);
  k_final<<<(G + TPB - 1) / TPB, TPB, 0, stream>>>(sums, gcnt, bfc, out, G);
}